// Round 1
// baseline (2595.408 us; speedup 1.0000x reference)
//
#include <hip/hip_runtime.h>

#define NN 40000
#define NE 640000
#define DD 128

// Transpose a 128x128 f32 matrix: WT[k][j] = W[j][k]
__global__ void transp_k(const float* __restrict__ W, float* __restrict__ WT) {
    int idx = blockIdx.x * 256 + threadIdx.x;  // 16384 total
    int j = idx >> 7, k = idx & 127;
    WT[k * DD + j] = W[j * DD + k];
}

__global__ void count_k(const int* __restrict__ dst, int* __restrict__ cnt) {
    int e = blockIdx.x * 256 + threadIdx.x;
    if (e < NE) atomicAdd(&cnt[dst[e]], 1);
}

__global__ void inv_k(const int* __restrict__ cnt, float* __restrict__ invc) {
    int i = blockIdx.x * 256 + threadIdx.x;
    if (i < NN) invc[i] = cnt[i] > 0 ? 1.0f / (float)cnt[i] : 0.0f;
}

// One (edge, 16B-chunk) per thread: gather x[src] row chunk, atomic-add into nbr[dst].
__global__ void scatter_k(const int* __restrict__ dst, const int* __restrict__ src,
                          const float* __restrict__ xin, float* __restrict__ nbr) {
    const long total = (long)NE * 32;  // 32 float4 chunks per 128-f32 row
    long stride = (long)gridDim.x * blockDim.x;
    for (long gid = (long)blockIdx.x * blockDim.x + threadIdx.x; gid < total; gid += stride) {
        int e = (int)(gid >> 5);
        int c = (int)(gid & 31);
        int s = src[e], d = dst[e];
        float4 v = ((const float4*)(xin + (long)s * DD))[c];
        float* p = nbr + (long)d * DD + (c << 2);
        atomicAdd(p + 0, v.x);
        atomicAdd(p + 1, v.y);
        atomicAdd(p + 2, v.z);
        atomicAdd(p + 3, v.w);
    }
}

// Fused: out[n] = relu(x@WsT + bs + mask*((nbr@WnT)*inv + bn))
// One wave per node. lane = (kh:1)(jcol:5); jj = 4 output cols, kh = k-half (0/64).
__global__ __launch_bounds__(256) void layer_k(
    const float* __restrict__ xin, const float* __restrict__ nbr,
    const float* __restrict__ invc,
    const float* __restrict__ WsT, const float* __restrict__ bs,
    const float* __restrict__ WnT, const float* __restrict__ bn,
    float* __restrict__ out) {
    int tid = threadIdx.x;
    int lane = tid & 63;
    int wave = tid >> 6;  // 0..3
    int node = blockIdx.x * 4 + wave;
    if (node >= NN) return;
    int jj = (lane & 31) << 2;  // 0,4,...,124
    int kh = (lane >> 5) << 6;  // 0 or 64

    const float* xr = xin + (long)node * DD + kh;
    const float* nr = nbr + (long)node * DD + kh;

    float accS0 = 0.f, accS1 = 0.f, accS2 = 0.f, accS3 = 0.f;
    float accN0 = 0.f, accN1 = 0.f, accN2 = 0.f, accN3 = 0.f;

    #pragma unroll 4
    for (int k = 0; k < 64; ++k) {
        int ke = k + kh;
        float4 ws = *(const float4*)(WsT + ke * DD + jj);
        float4 wn = *(const float4*)(WnT + ke * DD + jj);
        float xv = xr[k];
        float nv = nr[k];
        accS0 += xv * ws.x; accS1 += xv * ws.y; accS2 += xv * ws.z; accS3 += xv * ws.w;
        accN0 += nv * wn.x; accN1 += nv * wn.y; accN2 += nv * wn.z; accN3 += nv * wn.w;
    }

    // cross-half (k 0..63 vs 64..127) reduction
    accS0 += __shfl_xor(accS0, 32); accS1 += __shfl_xor(accS1, 32);
    accS2 += __shfl_xor(accS2, 32); accS3 += __shfl_xor(accS3, 32);
    accN0 += __shfl_xor(accN0, 32); accN1 += __shfl_xor(accN1, 32);
    accN2 += __shfl_xor(accN2, 32); accN3 += __shfl_xor(accN3, 32);

    if ((lane >> 5) == 0) {
        float inv = invc[node];
        float4 bsv = *(const float4*)(bs + jj);
        float4 bnv = *(const float4*)(bn + jj);
        float4 o;
        float m = inv > 0.f ? 1.f : 0.f;
        o.x = accS0 + bsv.x + m * (accN0 * inv + bnv.x);
        o.y = accS1 + bsv.y + m * (accN1 * inv + bnv.y);
        o.z = accS2 + bsv.z + m * (accN2 * inv + bnv.z);
        o.w = accS3 + bsv.w + m * (accN3 * inv + bnv.w);
        o.x = fmaxf(o.x, 0.f); o.y = fmaxf(o.y, 0.f);
        o.z = fmaxf(o.z, 0.f); o.w = fmaxf(o.w, 0.f);
        *(float4*)(out + (long)node * DD + jj) = o;
    }
}

extern "C" void kernel_launch(void* const* d_in, const int* in_sizes, int n_in,
                              void* d_out, int out_size, void* d_ws, size_t ws_size,
                              hipStream_t stream) {
    (void)in_sizes; (void)n_in; (void)out_size; (void)ws_size;
    const float* x   = (const float*)d_in[0];
    const int*   ei  = (const int*)d_in[1];   // [2, NE] int32: row0=dst, row1=src
    const float* Ws1 = (const float*)d_in[2];
    const float* bs1 = (const float*)d_in[3];
    const float* Wn1 = (const float*)d_in[4];
    const float* bn1 = (const float*)d_in[5];
    const float* Ws2 = (const float*)d_in[6];
    const float* bs2 = (const float*)d_in[7];
    const float* Wn2 = (const float*)d_in[8];
    const float* bn2 = (const float*)d_in[9];
    float* out = (float*)d_out;

    float* WsT1 = (float*)d_ws;            // 16384 f32 each
    float* WnT1 = WsT1 + 16384;
    float* WsT2 = WnT1 + 16384;
    float* WnT2 = WsT2 + 16384;
    int*   cnt  = (int*)(WnT2 + 16384);    // NN int
    float* invc = (float*)(cnt + NN);      // NN f32
    float* nbr  = invc + NN;               // NN*DD f32
    float* h    = nbr + (long)NN * DD;     // NN*DD f32

    const int* dstp = ei;
    const int* srcp = ei + NE;

    hipMemsetAsync(cnt, 0, NN * sizeof(int), stream);
    hipMemsetAsync(nbr, 0, (size_t)NN * DD * sizeof(float), stream);

    transp_k<<<64, 256, 0, stream>>>(Ws1, WsT1);
    transp_k<<<64, 256, 0, stream>>>(Wn1, WnT1);
    transp_k<<<64, 256, 0, stream>>>(Ws2, WsT2);
    transp_k<<<64, 256, 0, stream>>>(Wn2, WnT2);

    count_k<<<(NE + 255) / 256, 256, 0, stream>>>(dstp, cnt);
    inv_k<<<(NN + 255) / 256, 256, 0, stream>>>(cnt, invc);

    // Layer 1
    scatter_k<<<4096, 256, 0, stream>>>(dstp, srcp, x, nbr);
    layer_k<<<NN / 4, 256, 0, stream>>>(x, nbr, invc, WsT1, bs1, WnT1, bn1, h);

    // Layer 2
    hipMemsetAsync(nbr, 0, (size_t)NN * DD * sizeof(float), stream);
    scatter_k<<<4096, 256, 0, stream>>>(dstp, srcp, h, nbr);
    layer_k<<<NN / 4, 256, 0, stream>>>(h, nbr, invc, WsT2, bs2, WnT2, bn2, out);
}

// Round 2
// 622.755 us; speedup vs baseline: 4.1676x; 4.1676x over previous
//
#include <hip/hip_runtime.h>

#define NN 40000
#define NE 640000
#define DD 128

// Transpose four 128x128 f32 matrices: T[k][j] = W[j][k]
__global__ void transp4_k(const float* __restrict__ W0, float* __restrict__ T0,
                          const float* __restrict__ W1, float* __restrict__ T1,
                          const float* __restrict__ W2, float* __restrict__ T2,
                          const float* __restrict__ W3, float* __restrict__ T3) {
    int idx = blockIdx.x * 256 + threadIdx.x;  // 4*16384 total
    int m = idx >> 14;
    int r = idx & 16383;
    int j = r >> 7, k = r & 127;
    const float* W = m == 0 ? W0 : m == 1 ? W1 : m == 2 ? W2 : W3;
    float*       T = m == 0 ? T0 : m == 1 ? T1 : m == 2 ? T2 : T3;
    T[k * DD + j] = W[j * DD + k];
}

__global__ void count_k(const int* __restrict__ dst, int* __restrict__ cnt) {
    int e = blockIdx.x * 256 + threadIdx.x;
    if (e < NE) atomicAdd(&cnt[dst[e]], 1);
}

__global__ void inv_k(const int* __restrict__ cnt, float* __restrict__ invc) {
    int i = blockIdx.x * 256 + threadIdx.x;
    if (i < NN) invc[i] = cnt[i] > 0 ? 1.0f / (float)cnt[i] : 0.0f;
}

// Single-block exclusive prefix sum of cnt[NN] -> rowstart[NN+1]
__global__ __launch_bounds__(1024) void scan_k(const int* __restrict__ cnt,
                                               int* __restrict__ rowstart) {
    __shared__ int part[1024];
    int t = threadIdx.x;
    const int CH = (NN + 1023) / 1024;  // 40
    int base = t * CH;
    int s = 0;
    for (int i = 0; i < CH; ++i) {
        int idx = base + i;
        s += (idx < NN) ? cnt[idx] : 0;
    }
    part[t] = s;
    __syncthreads();
    for (int d = 1; d < 1024; d <<= 1) {  // inclusive Hillis-Steele
        int v = part[t];
        int add = (t >= d) ? part[t - d] : 0;
        __syncthreads();
        part[t] = v + add;
        __syncthreads();
    }
    int run = (t > 0) ? part[t - 1] : 0;
    for (int i = 0; i < CH; ++i) {
        int idx = base + i;
        if (idx < NN) {
            rowstart[idx] = run;
            run += cnt[idx];
        }
    }
    if (t == 1023) rowstart[NN] = part[1023];
}

// Counting-sort edges by dst: esrc[rowstart[d] ...] = src ids of d's neighbors
__global__ void fill_k(const int* __restrict__ dst, const int* __restrict__ src,
                       const int* __restrict__ rowstart, int* __restrict__ cursor,
                       int* __restrict__ esrc) {
    int e = blockIdx.x * 256 + threadIdx.x;
    if (e < NE) {
        int d = dst[e];
        int pos = rowstart[d] + atomicAdd(&cursor[d], 1);
        esrc[pos] = src[e];
    }
}

// Gather-sum: one wave per dst node, 2 f32 cols per lane. nbr = mean(x[neighbors])
__global__ __launch_bounds__(256) void agg_k(const int* __restrict__ rowstart,
                                             const int* __restrict__ esrc,
                                             const float* __restrict__ xin,
                                             const float* __restrict__ invc,
                                             float* __restrict__ nbr) {
    int wave = threadIdx.x >> 6, lane = threadIdx.x & 63;
    int node = blockIdx.x * 4 + wave;
    if (node >= NN) return;
    int beg = rowstart[node], end = rowstart[node + 1];
    const float2* xp = (const float2*)xin;
    float ax = 0.f, ay = 0.f;
    int i = beg;
    for (; i + 3 < end; i += 4) {
        int s0 = esrc[i], s1 = esrc[i + 1], s2 = esrc[i + 2], s3 = esrc[i + 3];
        float2 v0 = xp[(long)s0 * 64 + lane];
        float2 v1 = xp[(long)s1 * 64 + lane];
        float2 v2 = xp[(long)s2 * 64 + lane];
        float2 v3 = xp[(long)s3 * 64 + lane];
        ax += v0.x + v1.x + v2.x + v3.x;
        ay += v0.y + v1.y + v2.y + v3.y;
    }
    for (; i < end; ++i) {
        int s = esrc[i];
        float2 v = xp[(long)s * 64 + lane];
        ax += v.x; ay += v.y;
    }
    float inv = invc[node];
    float2 o = {ax * inv, ay * inv};
    ((float2*)nbr)[(long)node * 64 + lane] = o;
}

// Fused: out[n] = relu(x@WsT + bs + mask*(nbr_mean@WnT + bn))
// One wave per node. lane = (kh:1)(jcol:5); jj = 4 output cols, kh = k-half.
__global__ __launch_bounds__(256) void layer_k(
    const float* __restrict__ xin, const float* __restrict__ nbr,
    const float* __restrict__ invc,
    const float* __restrict__ WsT, const float* __restrict__ bs,
    const float* __restrict__ WnT, const float* __restrict__ bn,
    float* __restrict__ out) {
    int tid = threadIdx.x;
    int lane = tid & 63;
    int wave = tid >> 6;  // 0..3
    int node = blockIdx.x * 4 + wave;
    if (node >= NN) return;
    int jj = (lane & 31) << 2;  // 0,4,...,124
    int kh = (lane >> 5) << 6;  // 0 or 64

    const float* xr = xin + (long)node * DD + kh;
    const float* nr = nbr + (long)node * DD + kh;

    float accS0 = 0.f, accS1 = 0.f, accS2 = 0.f, accS3 = 0.f;
    float accN0 = 0.f, accN1 = 0.f, accN2 = 0.f, accN3 = 0.f;

    #pragma unroll 4
    for (int k = 0; k < 64; ++k) {
        int ke = k + kh;
        float4 ws = *(const float4*)(WsT + ke * DD + jj);
        float4 wn = *(const float4*)(WnT + ke * DD + jj);
        float xv = xr[k];
        float nv = nr[k];
        accS0 += xv * ws.x; accS1 += xv * ws.y; accS2 += xv * ws.z; accS3 += xv * ws.w;
        accN0 += nv * wn.x; accN1 += nv * wn.y; accN2 += nv * wn.z; accN3 += nv * wn.w;
    }

    accS0 += __shfl_xor(accS0, 32); accS1 += __shfl_xor(accS1, 32);
    accS2 += __shfl_xor(accS2, 32); accS3 += __shfl_xor(accS3, 32);
    accN0 += __shfl_xor(accN0, 32); accN1 += __shfl_xor(accN1, 32);
    accN2 += __shfl_xor(accN2, 32); accN3 += __shfl_xor(accN3, 32);

    if ((lane >> 5) == 0) {
        float inv = invc[node];
        float4 bsv = *(const float4*)(bs + jj);
        float4 bnv = *(const float4*)(bn + jj);
        float m = inv > 0.f ? 1.f : 0.f;
        float4 o;
        o.x = accS0 + bsv.x + m * (accN0 + bnv.x);
        o.y = accS1 + bsv.y + m * (accN1 + bnv.y);
        o.z = accS2 + bsv.z + m * (accN2 + bnv.z);
        o.w = accS3 + bsv.w + m * (accN3 + bnv.w);
        o.x = fmaxf(o.x, 0.f); o.y = fmaxf(o.y, 0.f);
        o.z = fmaxf(o.z, 0.f); o.w = fmaxf(o.w, 0.f);
        *(float4*)(out + (long)node * DD + jj) = o;
    }
}

extern "C" void kernel_launch(void* const* d_in, const int* in_sizes, int n_in,
                              void* d_out, int out_size, void* d_ws, size_t ws_size,
                              hipStream_t stream) {
    (void)in_sizes; (void)n_in; (void)out_size; (void)ws_size;
    const float* x   = (const float*)d_in[0];
    const int*   ei  = (const int*)d_in[1];   // [2, NE]: row0=dst, row1=src
    const float* Ws1 = (const float*)d_in[2];
    const float* bs1 = (const float*)d_in[3];
    const float* Wn1 = (const float*)d_in[4];
    const float* bn1 = (const float*)d_in[5];
    const float* Ws2 = (const float*)d_in[6];
    const float* bs2 = (const float*)d_in[7];
    const float* Wn2 = (const float*)d_in[8];
    const float* bn2 = (const float*)d_in[9];
    float* out = (float*)d_out;

    float* WsT1     = (float*)d_ws;              // 16384 f32 each
    float* WnT1     = WsT1 + 16384;
    float* WsT2     = WnT1 + 16384;
    float* WnT2     = WsT2 + 16384;
    int*   cnt      = (int*)(WnT2 + 16384);      // NN
    int*   cursor   = cnt + NN;                  // NN
    int*   rowstart = cursor + NN;               // NN+1
    int*   esrc     = rowstart + NN + 1;         // NE
    float* invc     = (float*)(esrc + NE);       // NN
    float* nbr      = invc + NN;                 // NN*DD
    float* h        = nbr + (long)NN * DD;       // NN*DD

    const int* dstp = ei;
    const int* srcp = ei + NE;

    hipMemsetAsync(cnt, 0, NN * sizeof(int), stream);
    hipMemsetAsync(cursor, 0, NN * sizeof(int), stream);

    transp4_k<<<256, 256, 0, stream>>>(Ws1, WsT1, Wn1, WnT1, Ws2, WsT2, Wn2, WnT2);

    count_k<<<(NE + 255) / 256, 256, 0, stream>>>(dstp, cnt);
    scan_k<<<1, 1024, 0, stream>>>(cnt, rowstart);
    inv_k<<<(NN + 255) / 256, 256, 0, stream>>>(cnt, invc);
    fill_k<<<(NE + 255) / 256, 256, 0, stream>>>(dstp, srcp, rowstart, cursor, esrc);

    // Layer 1
    agg_k<<<NN / 4, 256, 0, stream>>>(rowstart, esrc, x, invc, nbr);
    layer_k<<<NN / 4, 256, 0, stream>>>(x, nbr, invc, WsT1, bs1, WnT1, bn1, h);

    // Layer 2
    agg_k<<<NN / 4, 256, 0, stream>>>(rowstart, esrc, h, invc, nbr);
    layer_k<<<NN / 4, 256, 0, stream>>>(h, nbr, invc, WsT2, bs2, WnT2, bn2, out);
}

// Round 3
// 246.588 us; speedup vs baseline: 10.5253x; 2.5255x over previous
//
#include <hip/hip_runtime.h>

#define NN 40000
#define NE 640000
#define DD 128

typedef __attribute__((ext_vector_type(8))) short bf16x8;
typedef __attribute__((ext_vector_type(4))) float f32x4;

__device__ __forceinline__ ushort f2bf(float f) {
    union { float f; unsigned u; } v; v.f = f;
    unsigned r = v.u + 0x7fffu + ((v.u >> 16) & 1u);
    return (ushort)(r >> 16);
}
__device__ __forceinline__ float bflo(unsigned u) {
    union { unsigned u; float f; } v; v.u = u << 16; return v.f;
}
__device__ __forceinline__ float bfhi(unsigned u) {
    union { unsigned u; float f; } v; v.u = u & 0xffff0000u; return v.f;
}

// Build concat bf16 weights: w[j][k] = k<128 ? Ws[j][k] : Wn[j][k-128]. [128][256]
__global__ void prep_w_k(const float* __restrict__ Ws1, const float* __restrict__ Wn1,
                         const float* __restrict__ Ws2, const float* __restrict__ Wn2,
                         ushort* __restrict__ w1, ushort* __restrict__ w2) {
    int idx = blockIdx.x * 256 + threadIdx.x;  // 65536
    int m = idx >> 15;
    int r = idx & 32767;  // j*256 + k
    int j = r >> 8, k = r & 255;
    const float* Ws = m ? Ws2 : Ws1;
    const float* Wn = m ? Wn2 : Wn1;
    float v = (k < 128) ? Ws[j * 128 + k] : Wn[j * 128 + (k - 128)];
    (m ? w2 : w1)[r] = f2bf(v);
}

// f32 -> bf16, 4 elems/thread
__global__ void cvt_x_k(const float* __restrict__ x, ushort* __restrict__ xb) {
    int i = blockIdx.x * 256 + threadIdx.x;  // NN*DD/4 = 1.28M
    float4 v = ((const float4*)x)[i];
    ushort4 o;
    o.x = f2bf(v.x); o.y = f2bf(v.y); o.z = f2bf(v.z); o.w = f2bf(v.w);
    ((ushort4*)xb)[i] = o;
}

__global__ void count_k(const int* __restrict__ dst, int* __restrict__ cnt) {
    int e = blockIdx.x * 256 + threadIdx.x;
    if (e < NE) atomicAdd(&cnt[dst[e]], 1);
}

__global__ void inv_k(const int* __restrict__ cnt, float* __restrict__ invc) {
    int i = blockIdx.x * 256 + threadIdx.x;
    if (i < NN) invc[i] = cnt[i] > 0 ? 1.0f / (float)cnt[i] : 0.0f;
}

// Single-block exclusive prefix sum of cnt[NN] -> rowstart[NN+1]
__global__ __launch_bounds__(1024) void scan_k(const int* __restrict__ cnt,
                                               int* __restrict__ rowstart) {
    __shared__ int part[1024];
    int t = threadIdx.x;
    const int CH = (NN + 1023) / 1024;  // 40
    int base = t * CH;
    int s = 0;
    for (int i = 0; i < CH; ++i) {
        int idx = base + i;
        s += (idx < NN) ? cnt[idx] : 0;
    }
    part[t] = s;
    __syncthreads();
    for (int d = 1; d < 1024; d <<= 1) {
        int v = part[t];
        int add = (t >= d) ? part[t - d] : 0;
        __syncthreads();
        part[t] = v + add;
        __syncthreads();
    }
    int run = (t > 0) ? part[t - 1] : 0;
    for (int i = 0; i < CH; ++i) {
        int idx = base + i;
        if (idx < NN) {
            rowstart[idx] = run;
            run += cnt[idx];
        }
    }
    if (t == 1023) rowstart[NN] = part[1023];
}

__global__ void fill_k(const int* __restrict__ dst, const int* __restrict__ src,
                       const int* __restrict__ rowstart, int* __restrict__ cursor,
                       int* __restrict__ esrc) {
    int e = blockIdx.x * 256 + threadIdx.x;
    if (e < NE) {
        int d = dst[e];
        int pos = rowstart[d] + atomicAdd(&cursor[d], 1);
        esrc[pos] = src[e];
    }
}

// Gather-mean over bf16 rows: one wave per node, 2 cols (1 uint) per lane.
__global__ __launch_bounds__(256) void agg_k(const int* __restrict__ rowstart,
                                             const int* __restrict__ esrc,
                                             const ushort* __restrict__ xb,
                                             const float* __restrict__ invc,
                                             ushort* __restrict__ nbrb) {
    int wave = threadIdx.x >> 6, lane = threadIdx.x & 63;
    int node = blockIdx.x * 4 + wave;
    if (node >= NN) return;
    int beg = rowstart[node], end = rowstart[node + 1];
    const unsigned* xp = (const unsigned*)xb;
    float ax = 0.f, ay = 0.f;
    int i = beg;
    for (; i + 3 < end; i += 4) {
        int s0 = esrc[i], s1 = esrc[i + 1], s2 = esrc[i + 2], s3 = esrc[i + 3];
        unsigned v0 = xp[(long)s0 * 64 + lane];
        unsigned v1 = xp[(long)s1 * 64 + lane];
        unsigned v2 = xp[(long)s2 * 64 + lane];
        unsigned v3 = xp[(long)s3 * 64 + lane];
        ax += bflo(v0) + bflo(v1) + bflo(v2) + bflo(v3);
        ay += bfhi(v0) + bfhi(v1) + bfhi(v2) + bfhi(v3);
    }
    for (; i < end; ++i) {
        unsigned v = xp[(long)esrc[i] * 64 + lane];
        ax += bflo(v); ay += bfhi(v);
    }
    float inv = invc[node];
    unsigned o = (unsigned)f2bf(ax * inv) | ((unsigned)f2bf(ay * inv) << 16);
    ((unsigned*)nbrb)[(long)node * 64 + lane] = o;
}

// Fused layer GEMM: D[node][j] = relu( [xb|nbrb] @ Wcat^T + bs + mask*bn )
// Weights [128 rows(j)][256 k] bf16 in XOR-swizzled LDS. 4 waves x 16 nodes per block.
__global__ __launch_bounds__(256) void gemm_k(
    const ushort* __restrict__ xb, const ushort* __restrict__ nbrb,
    const float* __restrict__ invc, const ushort* __restrict__ wcat,
    const float* __restrict__ bs, const float* __restrict__ bn,
    float* __restrict__ outf, ushort* __restrict__ outb, int writebf) {
    __shared__ ushort wlds[32768];  // 64 KB
    int t = threadIdx.x;
    // Stage 64KB weights, swizzled: byte ^= ((row&7)<<4)
    #pragma unroll
    for (int i = 0; i < 16; ++i) {
        int lin = (i * 256 + t) * 8;      // ushort index
        int row = lin >> 8;
        int kb = (lin & 255) * 2;         // byte offset in row, 16B aligned
        int skb = kb ^ ((row & 7) << 4);
        bf16x8 v = *(const bf16x8*)(wcat + lin);
        *(bf16x8*)((char*)wlds + row * 512 + skb) = v;
    }
    __syncthreads();

    int wave = t >> 6, lane = t & 63;
    int nodeb = blockIdx.x * 64 + wave * 16;
    int arow = nodeb + (lane & 15);
    int koff = (lane >> 4) * 8;  // element offset within a 32-wide K chunk

    f32x4 acc[8];
    #pragma unroll
    for (int n = 0; n < 8; ++n) acc[n] = (f32x4){0.f, 0.f, 0.f, 0.f};

    const ushort* arx = xb + (long)arow * DD + koff;
    const ushort* arn = nbrb + (long)arow * DD + koff;

    #pragma unroll
    for (int kc = 0; kc < 8; ++kc) {
        const ushort* ap = (kc < 4) ? (arx + kc * 32) : (arn + (kc - 4) * 32);
        bf16x8 a = *(const bf16x8*)ap;
        int bkb = (kc * 32 + koff) * 2;  // byte k-offset in weight row
        #pragma unroll
        for (int nt = 0; nt < 8; ++nt) {
            int brow = nt * 16 + (lane & 15);
            int sb = bkb ^ ((brow & 7) << 4);
            bf16x8 b = *(const bf16x8*)((const char*)wlds + brow * 512 + sb);
            acc[nt] = __builtin_amdgcn_mfma_f32_16x16x32_bf16(a, b, acc[nt], 0, 0, 0);
        }
    }

    // Epilogue: C/D layout col=lane&15, row=(lane>>4)*4+r
    int col0 = lane & 15;
    int rbase = nodeb + (lane >> 4) * 4;
    #pragma unroll
    for (int r = 0; r < 4; ++r) {
        int node = rbase + r;
        float m = invc[node] > 0.f ? 1.f : 0.f;
        #pragma unroll
        for (int nt = 0; nt < 8; ++nt) {
            int col = nt * 16 + col0;
            float v = acc[nt][r] + bs[col] + m * bn[col];
            v = fmaxf(v, 0.f);
            if (writebf) outb[(long)node * DD + col] = f2bf(v);
            else         outf[(long)node * DD + col] = v;
        }
    }
}

extern "C" void kernel_launch(void* const* d_in, const int* in_sizes, int n_in,
                              void* d_out, int out_size, void* d_ws, size_t ws_size,
                              hipStream_t stream) {
    (void)in_sizes; (void)n_in; (void)out_size; (void)ws_size;
    const float* x   = (const float*)d_in[0];
    const int*   ei  = (const int*)d_in[1];
    const float* Ws1 = (const float*)d_in[2];
    const float* bs1 = (const float*)d_in[3];
    const float* Wn1 = (const float*)d_in[4];
    const float* bn1 = (const float*)d_in[5];
    const float* Ws2 = (const float*)d_in[6];
    const float* bs2 = (const float*)d_in[7];
    const float* Wn2 = (const float*)d_in[8];
    const float* bn2 = (const float*)d_in[9];
    float* out = (float*)d_out;

    // Workspace layout (16B-aligned chunks first)
    ushort* wcat1 = (ushort*)d_ws;                 // 32768
    ushort* wcat2 = wcat1 + 32768;                 // 32768
    ushort* xbb   = wcat2 + 32768;                 // NN*DD
    ushort* hb    = xbb + (long)NN * DD;           // NN*DD
    ushort* nbrb  = hb + (long)NN * DD;            // NN*DD
    int*   cnt      = (int*)(nbrb + (long)NN * DD);
    int*   cursor   = cnt + NN;
    int*   rowstart = cursor + NN;                 // NN+1
    int*   esrc     = rowstart + NN + 1;           // NE
    float* invc     = (float*)(esrc + NE);         // NN

    const int* dstp = ei;
    const int* srcp = ei + NE;

    hipMemsetAsync(cnt, 0, NN * sizeof(int), stream);
    hipMemsetAsync(cursor, 0, NN * sizeof(int), stream);

    prep_w_k<<<256, 256, 0, stream>>>(Ws1, Wn1, Ws2, Wn2, wcat1, wcat2);
    cvt_x_k<<<(NN * DD / 4) / 256, 256, 0, stream>>>(x, xbb);

    count_k<<<(NE + 255) / 256, 256, 0, stream>>>(dstp, cnt);
    scan_k<<<1, 1024, 0, stream>>>(cnt, rowstart);
    inv_k<<<(NN + 255) / 256, 256, 0, stream>>>(cnt, invc);
    fill_k<<<(NE + 255) / 256, 256, 0, stream>>>(dstp, srcp, rowstart, cursor, esrc);

    // Layer 1
    agg_k<<<(NN + 3) / 4, 256, 0, stream>>>(rowstart, esrc, xbb, invc, nbrb);
    gemm_k<<<NN / 64, 256, 0, stream>>>(xbb, nbrb, invc, wcat1, bs1, bn1,
                                        (float*)nullptr, hb, 1);
    // Layer 2
    agg_k<<<(NN + 3) / 4, 256, 0, stream>>>(rowstart, esrc, hb, invc, nbrb);
    gemm_k<<<NN / 64, 256, 0, stream>>>(hb, nbrb, invc, wcat2, bs2, bn2,
                                        out, (ushort*)nullptr, 0);
}

// Round 4
// 179.543 us; speedup vs baseline: 14.4556x; 1.3734x over previous
//
#include <hip/hip_runtime.h>

#define NN 40000
#define NE 640000
#define DD 128
#define NB 157  // ceil(NN/256)

typedef __attribute__((ext_vector_type(8))) short bf16x8;
typedef __attribute__((ext_vector_type(4))) float f32x4;

__device__ __forceinline__ ushort f2bf(float f) {
    union { float f; unsigned u; } v; v.f = f;
    unsigned r = v.u + 0x7fffu + ((v.u >> 16) & 1u);
    return (ushort)(r >> 16);
}
__device__ __forceinline__ float bflo(unsigned u) {
    union { unsigned u; float f; } v; v.u = u << 16; return v.f;
}
__device__ __forceinline__ float bfhi(unsigned u) {
    union { unsigned u; float f; } v; v.u = u & 0xffff0000u; return v.f;
}

__device__ __forceinline__ int wave_incl_scan(int v, int lane) {
    #pragma unroll
    for (int d = 1; d < 64; d <<= 1) {
        int u = __shfl_up(v, d);
        if (lane >= d) v += u;
    }
    return v;
}

// Build concat bf16 weights: w[j][k] = k<128 ? Ws[j][k] : Wn[j][k-128]. [128][256]
__global__ void prep_w_k(const float* __restrict__ Ws1, const float* __restrict__ Wn1,
                         const float* __restrict__ Ws2, const float* __restrict__ Wn2,
                         ushort* __restrict__ w1, ushort* __restrict__ w2) {
    int idx = blockIdx.x * 256 + threadIdx.x;  // 65536
    int m = idx >> 15;
    int r = idx & 32767;  // j*256 + k
    int j = r >> 8, k = r & 255;
    const float* Ws = m ? Ws2 : Ws1;
    const float* Wn = m ? Wn2 : Wn1;
    float v = (k < 128) ? Ws[j * 128 + k] : Wn[j * 128 + (k - 128)];
    (m ? w2 : w1)[r] = f2bf(v);
}

// f32 -> bf16, 4 elems/thread
__global__ void cvt_x_k(const float* __restrict__ x, ushort* __restrict__ xb) {
    int i = blockIdx.x * 256 + threadIdx.x;
    float4 v = ((const float4*)x)[i];
    ushort4 o;
    o.x = f2bf(v.x); o.y = f2bf(v.y); o.z = f2bf(v.z); o.w = f2bf(v.w);
    ((ushort4*)xb)[i] = o;
}

__global__ void count_k(const int* __restrict__ dst, int* __restrict__ cnt) {
    int e = blockIdx.x * 256 + threadIdx.x;
    if (e < NE) atomicAdd(&cnt[dst[e]], 1);
}

// Phase 1: block-local exclusive scan of cnt into rowstart; block sums to bsum.
__global__ __launch_bounds__(256) void scan1_k(const int* __restrict__ cnt,
                                               int* __restrict__ rowstart,
                                               int* __restrict__ bsum) {
    int b = blockIdx.x, t = threadIdx.x;
    int i = b * 256 + t;
    int lane = t & 63, wave = t >> 6;
    int v = (i < NN) ? cnt[i] : 0;
    int s = wave_incl_scan(v, lane);
    __shared__ int wsum[4];
    if (lane == 63) wsum[wave] = s;
    __syncthreads();
    int add = 0;
    #pragma unroll
    for (int w = 0; w < 3; ++w) add += (w < wave) ? wsum[w] : 0;
    int incl = s + add;
    if (i < NN) rowstart[i] = incl - v;  // block-local exclusive
    if (t == 255) bsum[b] = incl;        // block total
}

// Phase 2: single block scans bsum[NB] -> boff (exclusive); writes rowstart[NN]=NE.
__global__ __launch_bounds__(256) void scan2_k(const int* __restrict__ bsum,
                                               int* __restrict__ boff,
                                               int* __restrict__ rowstart) {
    int t = threadIdx.x;
    int lane = t & 63, wave = t >> 6;
    int v = (t < NB) ? bsum[t] : 0;
    int s = wave_incl_scan(v, lane);
    __shared__ int wsum[4];
    if (lane == 63) wsum[wave] = s;
    __syncthreads();
    int add = 0;
    #pragma unroll
    for (int w = 0; w < 3; ++w) add += (w < wave) ? wsum[w] : 0;
    int incl = s + add;
    if (t < NB) boff[t] = incl - v;
    if (t == 255) rowstart[NN] = incl;
}

// Phase 3: rowstart += block offset (in place); fused invc = 1/max(cnt,1) (0 if cnt=0).
__global__ __launch_bounds__(256) void scan3_k(int* __restrict__ rowstart,
                                               const int* __restrict__ boff,
                                               const int* __restrict__ cnt,
                                               float* __restrict__ invc) {
    int b = blockIdx.x, t = threadIdx.x;
    int i = b * 256 + t;
    if (i < NN) {
        rowstart[i] += boff[b];
        int c = cnt[i];
        invc[i] = c > 0 ? 1.0f / (float)c : 0.0f;
    }
}

__global__ void fill_k(const int* __restrict__ dst, const int* __restrict__ src,
                       const int* __restrict__ rowstart, int* __restrict__ cursor,
                       int* __restrict__ esrc) {
    int e = blockIdx.x * 256 + threadIdx.x;
    if (e < NE) {
        int d = dst[e];
        int pos = rowstart[d] + atomicAdd(&cursor[d], 1);
        esrc[pos] = src[e];
    }
}

// Gather-mean over bf16 rows: one wave per node, 2 cols (1 uint) per lane.
__global__ __launch_bounds__(256) void agg_k(const int* __restrict__ rowstart,
                                             const int* __restrict__ esrc,
                                             const ushort* __restrict__ xb,
                                             const float* __restrict__ invc,
                                             ushort* __restrict__ nbrb) {
    int wave = threadIdx.x >> 6, lane = threadIdx.x & 63;
    int node = blockIdx.x * 4 + wave;
    if (node >= NN) return;
    int beg = rowstart[node], end = rowstart[node + 1];
    const unsigned* xp = (const unsigned*)xb;
    float ax = 0.f, ay = 0.f;
    int i = beg;
    for (; i + 3 < end; i += 4) {
        int s0 = esrc[i], s1 = esrc[i + 1], s2 = esrc[i + 2], s3 = esrc[i + 3];
        unsigned v0 = xp[(long)s0 * 64 + lane];
        unsigned v1 = xp[(long)s1 * 64 + lane];
        unsigned v2 = xp[(long)s2 * 64 + lane];
        unsigned v3 = xp[(long)s3 * 64 + lane];
        ax += bflo(v0) + bflo(v1) + bflo(v2) + bflo(v3);
        ay += bfhi(v0) + bfhi(v1) + bfhi(v2) + bfhi(v3);
    }
    for (; i < end; ++i) {
        unsigned v = xp[(long)esrc[i] * 64 + lane];
        ax += bflo(v); ay += bfhi(v);
    }
    float inv = invc[node];
    unsigned o = (unsigned)f2bf(ax * inv) | ((unsigned)f2bf(ay * inv) << 16);
    ((unsigned*)nbrb)[(long)node * 64 + lane] = o;
}

// Fused layer GEMM: D[node][j] = relu( [xb|nbrb] @ Wcat^T + bs + mask*bn )
__global__ __launch_bounds__(256) void gemm_k(
    const ushort* __restrict__ xb, const ushort* __restrict__ nbrb,
    const float* __restrict__ invc, const ushort* __restrict__ wcat,
    const float* __restrict__ bs, const float* __restrict__ bn,
    float* __restrict__ outf, ushort* __restrict__ outb, int writebf) {
    __shared__ ushort wlds[32768];  // 64 KB
    int t = threadIdx.x;
    #pragma unroll
    for (int i = 0; i < 16; ++i) {
        int lin = (i * 256 + t) * 8;
        int row = lin >> 8;
        int kb = (lin & 255) * 2;
        int skb = kb ^ ((row & 7) << 4);
        bf16x8 v = *(const bf16x8*)(wcat + lin);
        *(bf16x8*)((char*)wlds + row * 512 + skb) = v;
    }
    __syncthreads();

    int wave = t >> 6, lane = t & 63;
    int nodeb = blockIdx.x * 64 + wave * 16;
    int arow = nodeb + (lane & 15);
    int koff = (lane >> 4) * 8;

    f32x4 acc[8];
    #pragma unroll
    for (int n = 0; n < 8; ++n) acc[n] = (f32x4){0.f, 0.f, 0.f, 0.f};

    const ushort* arx = xb + (long)arow * DD + koff;
    const ushort* arn = nbrb + (long)arow * DD + koff;

    #pragma unroll
    for (int kc = 0; kc < 8; ++kc) {
        const ushort* ap = (kc < 4) ? (arx + kc * 32) : (arn + (kc - 4) * 32);
        bf16x8 a = *(const bf16x8*)ap;
        int bkb = (kc * 32 + koff) * 2;
        #pragma unroll
        for (int nt = 0; nt < 8; ++nt) {
            int brow = nt * 16 + (lane & 15);
            int sb = bkb ^ ((brow & 7) << 4);
            bf16x8 b = *(const bf16x8*)((const char*)wlds + brow * 512 + sb);
            acc[nt] = __builtin_amdgcn_mfma_f32_16x16x32_bf16(a, b, acc[nt], 0, 0, 0);
        }
    }

    int col0 = lane & 15;
    int rbase = nodeb + (lane >> 4) * 4;
    #pragma unroll
    for (int r = 0; r < 4; ++r) {
        int node = rbase + r;
        float m = invc[node] > 0.f ? 1.f : 0.f;
        #pragma unroll
        for (int nt = 0; nt < 8; ++nt) {
            int col = nt * 16 + col0;
            float v = acc[nt][r] + bs[col] + m * bn[col];
            v = fmaxf(v, 0.f);
            if (writebf) outb[(long)node * DD + col] = f2bf(v);
            else         outf[(long)node * DD + col] = v;
        }
    }
}

extern "C" void kernel_launch(void* const* d_in, const int* in_sizes, int n_in,
                              void* d_out, int out_size, void* d_ws, size_t ws_size,
                              hipStream_t stream) {
    (void)in_sizes; (void)n_in; (void)out_size; (void)ws_size;
    const float* x   = (const float*)d_in[0];
    const int*   ei  = (const int*)d_in[1];
    const float* Ws1 = (const float*)d_in[2];
    const float* bs1 = (const float*)d_in[3];
    const float* Wn1 = (const float*)d_in[4];
    const float* bn1 = (const float*)d_in[5];
    const float* Ws2 = (const float*)d_in[6];
    const float* bs2 = (const float*)d_in[7];
    const float* Wn2 = (const float*)d_in[8];
    const float* bn2 = (const float*)d_in[9];
    float* out = (float*)d_out;

    ushort* wcat1 = (ushort*)d_ws;                 // 32768
    ushort* wcat2 = wcat1 + 32768;                 // 32768
    ushort* xbb   = wcat2 + 32768;                 // NN*DD
    ushort* hb    = xbb + (long)NN * DD;           // NN*DD
    ushort* nbrb  = hb + (long)NN * DD;            // NN*DD
    int*   cnt      = (int*)(nbrb + (long)NN * DD);
    int*   cursor   = cnt + NN;
    int*   rowstart = cursor + NN;                 // NN+1
    int*   esrc     = rowstart + NN + 1;           // NE
    float* invc     = (float*)(esrc + NE);         // NN
    int*   bsum     = (int*)(invc + NN);           // 256
    int*   boff     = bsum + 256;                  // 256

    const int* dstp = ei;
    const int* srcp = ei + NE;

    hipMemsetAsync(cnt, 0, NN * sizeof(int), stream);
    hipMemsetAsync(cursor, 0, NN * sizeof(int), stream);

    prep_w_k<<<256, 256, 0, stream>>>(Ws1, Wn1, Ws2, Wn2, wcat1, wcat2);
    cvt_x_k<<<(NN * DD / 4) / 256, 256, 0, stream>>>(x, xbb);

    count_k<<<(NE + 255) / 256, 256, 0, stream>>>(dstp, cnt);
    scan1_k<<<NB, 256, 0, stream>>>(cnt, rowstart, bsum);
    scan2_k<<<1, 256, 0, stream>>>(bsum, boff, rowstart);
    scan3_k<<<NB, 256, 0, stream>>>(rowstart, boff, cnt, invc);
    fill_k<<<(NE + 255) / 256, 256, 0, stream>>>(dstp, srcp, rowstart, cursor, esrc);

    // Layer 1
    agg_k<<<(NN + 3) / 4, 256, 0, stream>>>(rowstart, esrc, xbb, invc, nbrb);
    gemm_k<<<NN / 64, 256, 0, stream>>>(xbb, nbrb, invc, wcat1, bs1, bn1,
                                        (float*)nullptr, hb, 1);
    // Layer 2
    agg_k<<<(NN + 3) / 4, 256, 0, stream>>>(rowstart, esrc, hb, invc, nbrb);
    gemm_k<<<NN / 64, 256, 0, stream>>>(hb, nbrb, invc, wcat2, bs2, bn2,
                                        out, (ushort*)nullptr, 0);
}

// Round 5
// 178.720 us; speedup vs baseline: 14.5222x; 1.0046x over previous
//
#include <hip/hip_runtime.h>

#define NN 40000
#define NE 640000
#define DD 128
#define NB 157  // ceil(NN/256)

typedef __attribute__((ext_vector_type(8))) short bf16x8;
typedef __attribute__((ext_vector_type(4))) float f32x4;

__device__ __forceinline__ ushort f2bf(float f) {
    union { float f; unsigned u; } v; v.f = f;
    unsigned r = v.u + 0x7fffu + ((v.u >> 16) & 1u);
    return (ushort)(r >> 16);
}
__device__ __forceinline__ float bflo(unsigned u) {
    union { unsigned u; float f; } v; v.u = u << 16; return v.f;
}
__device__ __forceinline__ float bfhi(unsigned u) {
    union { unsigned u; float f; } v; v.u = u & 0xffff0000u; return v.f;
}

__device__ __forceinline__ int wave_incl_scan(int v, int lane) {
    #pragma unroll
    for (int d = 1; d < 64; d <<= 1) {
        int u = __shfl_up(v, d);
        if (lane >= d) v += u;
    }
    return v;
}

__global__ __launch_bounds__(256) void zero_k(int* __restrict__ p, int n) {
    int i = blockIdx.x * 256 + threadIdx.x;
    if (i < n) p[i] = 0;
}

// Build concat bf16 weights: w[j][k] = k<128 ? Ws[j][k] : Wn[j][k-128]. [128][256]
__global__ void prep_w_k(const float* __restrict__ Ws1, const float* __restrict__ Wn1,
                         const float* __restrict__ Ws2, const float* __restrict__ Wn2,
                         ushort* __restrict__ w1, ushort* __restrict__ w2) {
    int idx = blockIdx.x * 256 + threadIdx.x;  // 65536
    int m = idx >> 15;
    int r = idx & 32767;  // j*256 + k
    int j = r >> 8, k = r & 255;
    const float* Ws = m ? Ws2 : Ws1;
    const float* Wn = m ? Wn2 : Wn1;
    float v = (k < 128) ? Ws[j * 128 + k] : Wn[j * 128 + (k - 128)];
    (m ? w2 : w1)[r] = f2bf(v);
}

// f32 -> bf16, 4 elems/thread
__global__ void cvt_x_k(const float* __restrict__ x, ushort* __restrict__ xb) {
    int i = blockIdx.x * 256 + threadIdx.x;
    float4 v = ((const float4*)x)[i];
    ushort4 o;
    o.x = f2bf(v.x); o.y = f2bf(v.y); o.z = f2bf(v.z); o.w = f2bf(v.w);
    ((ushort4*)xb)[i] = o;
}

__global__ void count_k(const int* __restrict__ dst, int* __restrict__ cnt) {
    int e = blockIdx.x * 256 + threadIdx.x;
    if (e < NE) atomicAdd(&cnt[dst[e]], 1);
}

// Phase 1: block-local exclusive scan of cnt into rowstart; block sums to bsum.
__global__ __launch_bounds__(256) void scan1_k(const int* __restrict__ cnt,
                                               int* __restrict__ rowstart,
                                               int* __restrict__ bsum) {
    int b = blockIdx.x, t = threadIdx.x;
    int i = b * 256 + t;
    int lane = t & 63, wave = t >> 6;
    int v = (i < NN) ? cnt[i] : 0;
    int s = wave_incl_scan(v, lane);
    __shared__ int wsum[4];
    if (lane == 63) wsum[wave] = s;
    __syncthreads();
    int add = 0;
    #pragma unroll
    for (int w = 0; w < 3; ++w) add += (w < wave) ? wsum[w] : 0;
    int incl = s + add;
    if (i < NN) rowstart[i] = incl - v;  // block-local exclusive
    if (t == 255) bsum[b] = incl;        // block total
}

// Phase 2: single block scans bsum[NB] -> boff (exclusive); writes rowstart[NN]=NE.
__global__ __launch_bounds__(256) void scan2_k(const int* __restrict__ bsum,
                                               int* __restrict__ boff,
                                               int* __restrict__ rowstart) {
    int t = threadIdx.x;
    int lane = t & 63, wave = t >> 6;
    int v = (t < NB) ? bsum[t] : 0;
    int s = wave_incl_scan(v, lane);
    __shared__ int wsum[4];
    if (lane == 63) wsum[wave] = s;
    __syncthreads();
    int add = 0;
    #pragma unroll
    for (int w = 0; w < 3; ++w) add += (w < wave) ? wsum[w] : 0;
    int incl = s + add;
    if (t < NB) boff[t] = incl - v;
    if (t == 255) rowstart[NN] = incl;
}

// Phase 3: rowstart += block offset (in place); cursor = rowstart; invc = 1/cnt.
__global__ __launch_bounds__(256) void scan3_k(int* __restrict__ rowstart,
                                               const int* __restrict__ boff,
                                               const int* __restrict__ cnt,
                                               int* __restrict__ cursor,
                                               float* __restrict__ invc) {
    int b = blockIdx.x, t = threadIdx.x;
    int i = b * 256 + t;
    if (i < NN) {
        int rs = rowstart[i] + boff[b];
        rowstart[i] = rs;
        cursor[i] = rs;
        int c = cnt[i];
        invc[i] = c > 0 ? 1.0f / (float)c : 0.0f;
    }
}

// Counting-sort edges by dst; cursor pre-seeded with rowstart.
__global__ void fill_k(const int* __restrict__ dst, const int* __restrict__ src,
                       int* __restrict__ cursor, int* __restrict__ esrc) {
    int e = blockIdx.x * 256 + threadIdx.x;
    if (e < NE) {
        int pos = atomicAdd(&cursor[dst[e]], 1);
        esrc[pos] = src[e];
    }
}

// Gather-mean over bf16 rows: one wave per node, 2 cols (1 uint) per lane.
__global__ __launch_bounds__(256) void agg_k(const int* __restrict__ rowstart,
                                             const int* __restrict__ esrc,
                                             const ushort* __restrict__ xb,
                                             const float* __restrict__ invc,
                                             ushort* __restrict__ nbrb) {
    int wave = threadIdx.x >> 6, lane = threadIdx.x & 63;
    int node = blockIdx.x * 4 + wave;
    if (node >= NN) return;
    int beg = rowstart[node], end = rowstart[node + 1];
    const unsigned* xp = (const unsigned*)xb;
    float ax = 0.f, ay = 0.f;
    int i = beg;
    for (; i + 3 < end; i += 4) {
        int s0 = esrc[i], s1 = esrc[i + 1], s2 = esrc[i + 2], s3 = esrc[i + 3];
        unsigned v0 = xp[(long)s0 * 64 + lane];
        unsigned v1 = xp[(long)s1 * 64 + lane];
        unsigned v2 = xp[(long)s2 * 64 + lane];
        unsigned v3 = xp[(long)s3 * 64 + lane];
        ax += bflo(v0) + bflo(v1) + bflo(v2) + bflo(v3);
        ay += bfhi(v0) + bfhi(v1) + bfhi(v2) + bfhi(v3);
    }
    for (; i < end; ++i) {
        unsigned v = xp[(long)esrc[i] * 64 + lane];
        ax += bflo(v); ay += bfhi(v);
    }
    float inv = invc[node];
    unsigned o = (unsigned)f2bf(ax * inv) | ((unsigned)f2bf(ay * inv) << 16);
    ((unsigned*)nbrb)[(long)node * 64 + lane] = o;
}

// Fused layer GEMM: D[node][j] = relu( [xb|nbrb] @ Wcat^T + bs + mask*bn )
__global__ __launch_bounds__(256) void gemm_k(
    const ushort* __restrict__ xb, const ushort* __restrict__ nbrb,
    const float* __restrict__ invc, const ushort* __restrict__ wcat,
    const float* __restrict__ bs, const float* __restrict__ bn,
    float* __restrict__ outf, ushort* __restrict__ outb, int writebf) {
    __shared__ ushort wlds[32768];  // 64 KB
    int t = threadIdx.x;
    #pragma unroll
    for (int i = 0; i < 16; ++i) {
        int lin = (i * 256 + t) * 8;
        int row = lin >> 8;
        int kb = (lin & 255) * 2;
        int skb = kb ^ ((row & 7) << 4);
        bf16x8 v = *(const bf16x8*)(wcat + lin);
        *(bf16x8*)((char*)wlds + row * 512 + skb) = v;
    }
    __syncthreads();

    int wave = t >> 6, lane = t & 63;
    int nodeb = blockIdx.x * 64 + wave * 16;
    int arow = nodeb + (lane & 15);
    int koff = (lane >> 4) * 8;

    f32x4 acc[8];
    #pragma unroll
    for (int n = 0; n < 8; ++n) acc[n] = (f32x4){0.f, 0.f, 0.f, 0.f};

    const ushort* arx = xb + (long)arow * DD + koff;
    const ushort* arn = nbrb + (long)arow * DD + koff;

    #pragma unroll
    for (int kc = 0; kc < 8; ++kc) {
        const ushort* ap = (kc < 4) ? (arx + kc * 32) : (arn + (kc - 4) * 32);
        bf16x8 a = *(const bf16x8*)ap;
        int bkb = (kc * 32 + koff) * 2;
        #pragma unroll
        for (int nt = 0; nt < 8; ++nt) {
            int brow = nt * 16 + (lane & 15);
            int sb = bkb ^ ((brow & 7) << 4);
            bf16x8 b = *(const bf16x8*)((const char*)wlds + brow * 512 + sb);
            acc[nt] = __builtin_amdgcn_mfma_f32_16x16x32_bf16(a, b, acc[nt], 0, 0, 0);
        }
    }

    int col0 = lane & 15;
    int rbase = nodeb + (lane >> 4) * 4;
    #pragma unroll
    for (int r = 0; r < 4; ++r) {
        int node = rbase + r;
        float m = invc[node] > 0.f ? 1.f : 0.f;
        #pragma unroll
        for (int nt = 0; nt < 8; ++nt) {
            int col = nt * 16 + col0;
            float v = acc[nt][r] + bs[col] + m * bn[col];
            v = fmaxf(v, 0.f);
            if (writebf) outb[(long)node * DD + col] = f2bf(v);
            else         outf[(long)node * DD + col] = v;
        }
    }
}

extern "C" void kernel_launch(void* const* d_in, const int* in_sizes, int n_in,
                              void* d_out, int out_size, void* d_ws, size_t ws_size,
                              hipStream_t stream) {
    (void)in_sizes; (void)n_in; (void)out_size; (void)ws_size;
    const float* x   = (const float*)d_in[0];
    const int*   ei  = (const int*)d_in[1];
    const float* Ws1 = (const float*)d_in[2];
    const float* bs1 = (const float*)d_in[3];
    const float* Wn1 = (const float*)d_in[4];
    const float* bn1 = (const float*)d_in[5];
    const float* Ws2 = (const float*)d_in[6];
    const float* bs2 = (const float*)d_in[7];
    const float* Wn2 = (const float*)d_in[8];
    const float* bn2 = (const float*)d_in[9];
    float* out = (float*)d_out;

    ushort* wcat1 = (ushort*)d_ws;                 // 32768
    ushort* wcat2 = wcat1 + 32768;                 // 32768
    ushort* xbb   = wcat2 + 32768;                 // NN*DD
    ushort* hb    = xbb + (long)NN * DD;           // NN*DD
    ushort* nbrb  = hb + (long)NN * DD;            // NN*DD
    int*   cnt      = (int*)(nbrb + (long)NN * DD);
    int*   cursor   = cnt + NN;
    int*   rowstart = cursor + NN;                 // NN+1
    int*   esrc     = rowstart + NN + 1;           // NE
    float* invc     = (float*)(esrc + NE);         // NN
    int*   bsum     = (int*)(invc + NN);           // 256
    int*   boff     = bsum + 256;                  // 256

    const int* dstp = ei;
    const int* srcp = ei + NE;

    zero_k<<<NB, 256, 0, stream>>>(cnt, NN);
    prep_w_k<<<256, 256, 0, stream>>>(Ws1, Wn1, Ws2, Wn2, wcat1, wcat2);
    cvt_x_k<<<(NN * DD / 4) / 256, 256, 0, stream>>>(x, xbb);

    count_k<<<(NE + 255) / 256, 256, 0, stream>>>(dstp, cnt);
    scan1_k<<<NB, 256, 0, stream>>>(cnt, rowstart, bsum);
    scan2_k<<<1, 256, 0, stream>>>(bsum, boff, rowstart);
    scan3_k<<<NB, 256, 0, stream>>>(rowstart, boff, cnt, cursor, invc);
    fill_k<<<(NE + 255) / 256, 256, 0, stream>>>(dstp, srcp, cursor, esrc);

    // Layer 1
    agg_k<<<(NN + 3) / 4, 256, 0, stream>>>(rowstart, esrc, xbb, invc, nbrb);
    gemm_k<<<NN / 64, 256, 0, stream>>>(xbb, nbrb, invc, wcat1, bs1, bn1,
                                        (float*)nullptr, hb, 1);
    // Layer 2
    agg_k<<<(NN + 3) / 4, 256, 0, stream>>>(rowstart, esrc, hb, invc, nbrb);
    gemm_k<<<NN / 64, 256, 0, stream>>>(hb, nbrb, invc, wcat2, bs2, bn2,
                                        out, (ushort*)nullptr, 0);
}